// Round 4
// baseline (199.666 us; speedup 1.0000x reference)
//
#include <hip/hip_runtime.h>
#include <hip/hip_bf16.h>

#define N_NODES 4096
#define IN_DIM  256
#define OUT_DIM 128
#define EDGE_DIM 64
#define N_SAMPLE 128

__device__ __forceinline__ float wsum64(float v) {
#pragma unroll
  for (int off = 32; off; off >>= 1) v += __shfl_xor(v, off, 64);
  return v;
}
__device__ __forceinline__ float wmax64(float v) {
#pragma unroll
  for (int off = 32; off; off >>= 1) v = fmaxf(v, __shfl_xor(v, off, 64));
  return v;
}

// ---------------- x = features @ W  (4096x256 @ 256x128) ----------------
__global__ void __launch_bounds__(128) gemm_x_kernel(const float* __restrict__ feat,
                                                     const float* __restrict__ W,
                                                     float* __restrict__ x) {
  const int t  = threadIdx.x;
  const int v0 = blockIdx.x * 8;
  __shared__ float f[8][IN_DIM];
  float* fflat = &f[0][0];
  for (int idx = t; idx < 8 * IN_DIM; idx += 128)
    fflat[idx] = feat[v0 * IN_DIM + idx];
  __syncthreads();
  float acc[8] = {0.f, 0.f, 0.f, 0.f, 0.f, 0.f, 0.f, 0.f};
  for (int i = 0; i < IN_DIM; i += 4) {
    const float w0 = W[(i + 0) * OUT_DIM + t];
    const float w1 = W[(i + 1) * OUT_DIM + t];
    const float w2 = W[(i + 2) * OUT_DIM + t];
    const float w3 = W[(i + 3) * OUT_DIM + t];
#pragma unroll
    for (int r = 0; r < 8; ++r) {
      const float4 fv = *reinterpret_cast<const float4*>(&f[r][i]);
      acc[r] += fv.x * w0 + fv.y * w1 + fv.z * w2 + fv.w * w3;
    }
  }
#pragma unroll
  for (int r = 0; r < 8; ++r) x[(v0 + r) * OUT_DIM + t] = acc[r];
}

// ---------------- s1[v] = x[v].a1, s2[v] = x[v].a2 ----------------
__global__ void __launch_bounds__(64) s12_kernel(const float* __restrict__ x,
                                                 const float* __restrict__ a,
                                                 float* __restrict__ s1,
                                                 float* __restrict__ s2) {
  const int v = blockIdx.x, l = threadIdx.x;
  const float x0 = x[v * OUT_DIM + l], x1 = x[v * OUT_DIM + 64 + l];
  float c1 = x0 * a[l] + x1 * a[64 + l];
  float c2 = x0 * a[OUT_DIM + l] + x1 * a[OUT_DIM + 64 + l];
  c1 = wsum64(c1);
  c2 = wsum64(c2);
  if (l == 0) { s1[v] = c1; s2[v] = c2; }
}

// ---------------- s3[r] = emb[r].a3  (rows = n+1) ----------------
__global__ void __launch_bounds__(256) s3_kernel(const float* __restrict__ emb,
                                                 const float* __restrict__ a,
                                                 float* __restrict__ s3, int rows) {
  const int w = threadIdx.x >> 6, l = threadIdx.x & 63;
  const int r = blockIdx.x * 4 + w;
  if (r >= rows) return;
  float c = emb[r * EDGE_DIM + l] * a[2 * OUT_DIM + l];
  c = wsum64(c);
  if (l == 0) s3[r] = c;
}

// ---------------- attention + aggregate + ELU ----------------
// 256 threads (4 waves) per node. Waves 0-1: logits+softmax (1 sample/thread).
// Aggregation: each wave owns 32 samples, lane owns 2 cols; LDS partial reduce.
// Serial gather chain per wave = 32 iters; 32 waves/CU for latency hiding.
__global__ void __launch_bounds__(256) attn_kernel(const float* __restrict__ x,
                                                   const float* __restrict__ s1,
                                                   const float* __restrict__ s2,
                                                   const float* __restrict__ s3,
                                                   const int* __restrict__ neigh,
                                                   const int* __restrict__ eidx,
                                                   float* __restrict__ out) {
  const int v = blockIdx.x;
  const int t = threadIdx.x;              // 0..255
  const int w = t >> 6, l = t & 63;
  __shared__ float att[N_SAMPLE];
  __shared__ int   us[N_SAMPLE];
  __shared__ float red[4];
  __shared__ float2 hpart[4][64];

  // ---- phase 1a: raw logits (waves 0,1) ----
  if (t < N_SAMPLE) {
    const int u = neigh[v * N_SAMPLE + t];
    us[t] = u;
    float e = s1[v] + s2[u] + s3[eidx[v * N_NODES + u]];
    e = e > 0.f ? e : 0.2f * e;           // leaky_relu alpha=0.2
    att[t] = e;
    const float m = wmax64(e);
    if (l == 0) red[w] = m;
  }
  __syncthreads();
  const float m = fmaxf(red[0], red[1]);
  // ---- phase 1b: exp + sum (waves 0,1) ----
  if (t < N_SAMPLE) {
    const float p = __expf(att[t] - m);
    att[t] = p;
    const float s = wsum64(p);
    if (l == 0) red[2 + w] = s;
  }
  __syncthreads();
  const float inv = 1.0f / (red[2] + red[3]);

  // ---- phase 2: aggregation, sample-split across 4 waves ----
  float2 h = make_float2(0.f, 0.f);
  const int s0 = w * 32;
#pragma unroll 8
  for (int s = s0; s < s0 + 32; ++s) {
    const float a = att[s];
    const float2 xv = *reinterpret_cast<const float2*>(&x[us[s] * OUT_DIM + 2 * l]);
    h.x += a * xv.x;
    h.y += a * xv.y;
  }
  hpart[w][l] = h;
  __syncthreads();

  if (t < 64) {
    float2 H = hpart[0][t];
    const float2 p1 = hpart[1][t], p2 = hpart[2][t], p3 = hpart[3][t];
    H.x += p1.x + p2.x + p3.x;
    H.y += p1.y + p2.y + p3.y;
    const float2 xs = *reinterpret_cast<const float2*>(&x[v * OUT_DIM + 2 * t]);
    float ox = H.x * inv + xs.x;
    float oy = H.y * inv + xs.y;
    ox = ox > 0.f ? ox : expm1f(ox);      // ELU
    oy = oy > 0.f ? oy : expm1f(oy);
    float2 r = make_float2(ox, oy);
    *reinterpret_cast<float2*>(&out[v * OUT_DIM + 2 * t]) = r;
  }
}

// ---------------- Y = out @ W2  (4096x128 @ 128x64) ----------------
__global__ void __launch_bounds__(256) y_kernel(const float* __restrict__ out,
                                                const float* __restrict__ W2,
                                                float* __restrict__ Y) {
  const int t  = threadIdx.x;
  const int r0 = blockIdx.x * 16;
  __shared__ float o[16][132];
  for (int idx = t; idx < 16 * OUT_DIM; idx += 256)
    o[idx >> 7][idx & 127] = out[r0 * OUT_DIM + idx];
  __syncthreads();
  const int r  = t >> 4;
  const int c0 = (t & 15) * 4;
  float4 acc = make_float4(0.f, 0.f, 0.f, 0.f);
  for (int k = 0; k < OUT_DIM; k += 4) {
#pragma unroll
    for (int kk = 0; kk < 4; ++kk) {
      const float av = o[r][k + kk];
      const float4 w = *reinterpret_cast<const float4*>(&W2[(k + kk) * EDGE_DIM + c0]);
      acc.x += av * w.x; acc.y += av * w.y; acc.z += av * w.z; acc.w += av * w.w;
    }
  }
  *reinterpret_cast<float4*>(&Y[(r0 + r) * EDGE_DIM + c0]) = acc;
}

// ---------------- fused edge update ----------------
// emb_new[k+1] = relu((emb[eid[k]] @ W3 + Y[i]+Y[j] + B) * emb[k+1])
#define TE 64
__global__ void __launch_bounds__(256) edge_fused_kernel(const float* __restrict__ Y,
                                                         const float* __restrict__ emb,
                                                         const int* __restrict__ eidx,
                                                         const int* __restrict__ tu,
                                                         const float* __restrict__ W3,
                                                         const float* __restrict__ Bv,
                                                         float* __restrict__ emb_new, int n) {
  const int t  = threadIdx.x;
  const int k0 = blockIdx.x * TE;
  __shared__ float Ain[TE][68];
  __shared__ int   tus[2 * TE];

  if (t < 2 * TE) {
    const int idx = 2 * k0 + t;
    tus[t] = (idx < 2 * n) ? tu[idx] : 0;
  }
  {
    const int e  = t >> 2, q = t & 3;
    const int ke = k0 + e;
    if (ke < n) {
      const int i = tu[2 * ke], j = tu[2 * ke + 1];
      const int id = eidx[i * N_NODES + j];
#pragma unroll
      for (int kk = 0; kk < 16; kk += 4) {
        const int k = q * 16 + kk;
        *reinterpret_cast<float4*>(&Ain[e][k]) =
            *reinterpret_cast<const float4*>(&emb[id * EDGE_DIM + k]);
      }
    }
  }
  __syncthreads();

  const int e0 = (t >> 4) * 4;
  const int c0 = (t & 15) * 4;
  const float4 b4 = *reinterpret_cast<const float4*>(&Bv[c0]);
  float4 acc[4];
#pragma unroll
  for (int m = 0; m < 4; ++m) acc[m] = b4;

#pragma unroll 4
  for (int k = 0; k < EDGE_DIM; k += 4) {
    float4 a[4];
#pragma unroll
    for (int m = 0; m < 4; ++m) a[m] = *reinterpret_cast<const float4*>(&Ain[e0 + m][k]);
#pragma unroll
    for (int kk = 0; kk < 4; ++kk) {
      const float4 w = *reinterpret_cast<const float4*>(&W3[(k + kk) * EDGE_DIM + c0]);
#pragma unroll
      for (int m = 0; m < 4; ++m) {
        const float av = reinterpret_cast<const float*>(&a[m])[kk];
        acc[m].x += av * w.x; acc[m].y += av * w.y; acc[m].z += av * w.z; acc[m].w += av * w.w;
      }
    }
  }

#pragma unroll
  for (int m = 0; m < 4; ++m) {
    const int ke = k0 + e0 + m;
    if (ke < n) {
      const int i = tus[2 * (e0 + m)], j = tus[2 * (e0 + m) + 1];
      const float4 yi = *reinterpret_cast<const float4*>(&Y[i * EDGE_DIM + c0]);
      const float4 yj = *reinterpret_cast<const float4*>(&Y[j * EDGE_DIM + c0]);
      const float4 ek = *reinterpret_cast<const float4*>(&emb[(ke + 1) * EDGE_DIM + c0]);
      float4 r;
      r.x = fmaxf((acc[m].x + yi.x + yj.x) * ek.x, 0.f);
      r.y = fmaxf((acc[m].y + yi.y + yj.y) * ek.y, 0.f);
      r.z = fmaxf((acc[m].z + yi.z + yj.z) * ek.z, 0.f);
      r.w = fmaxf((acc[m].w + yi.w + yj.w) * ek.w, 0.f);
      *reinterpret_cast<float4*>(&emb_new[(ke + 1) * EDGE_DIM + c0]) = r;
    }
  }
  if (blockIdx.x == 0 && t < 16) {
    const int cc = t * 4;
    const float4 b0 = *reinterpret_cast<const float4*>(&Bv[cc]);
    const float4 e0v = *reinterpret_cast<const float4*>(&emb[cc]);
    float4 r;
    r.x = fmaxf(b0.x * e0v.x, 0.f);
    r.y = fmaxf(b0.y * e0v.y, 0.f);
    r.z = fmaxf(b0.z * e0v.z, 0.f);
    r.w = fmaxf(b0.w * e0v.w, 0.f);
    *reinterpret_cast<float4*>(&emb_new[cc]) = r;
  }
}

extern "C" void kernel_launch(void* const* d_in, const int* in_sizes, int n_in,
                              void* d_out, int out_size, void* d_ws, size_t ws_size,
                              hipStream_t stream) {
  const float* feat  = (const float*)d_in[0];
  const int*   eidx  = (const int*)d_in[1];
  const int*   neigh = (const int*)d_in[2];
  const int*   tu    = (const int*)d_in[3];
  const float* emb   = (const float*)d_in[4];
  const float* W     = (const float*)d_in[5];
  const float* W2    = (const float*)d_in[6];
  const float* W3    = (const float*)d_in[7];
  const float* Bv    = (const float*)d_in[8];
  const float* a     = (const float*)d_in[9];
  const int n    = in_sizes[3] / 2;
  const int rows = in_sizes[4] / EDGE_DIM;

  float* x  = (float*)d_ws;
  float* s1 = x + N_NODES * OUT_DIM;
  float* s2 = s1 + N_NODES;
  float* s3 = s2 + N_NODES;
  float* Y  = s3 + ((rows + 3) & ~3);

  float* out_nodes = (float*)d_out;
  float* emb_new   = out_nodes + N_NODES * OUT_DIM;

  hipLaunchKernelGGL(gemm_x_kernel, dim3(N_NODES / 8), dim3(128), 0, stream, feat, W, x);
  hipLaunchKernelGGL(s12_kernel, dim3(N_NODES), dim3(64), 0, stream, x, a, s1, s2);
  hipLaunchKernelGGL(s3_kernel, dim3((rows + 3) / 4), dim3(256), 0, stream, emb, a, s3, rows);
  hipLaunchKernelGGL(attn_kernel, dim3(N_NODES), dim3(256), 0, stream,
                     x, s1, s2, s3, neigh, eidx, out_nodes);
  hipLaunchKernelGGL(y_kernel, dim3(N_NODES / 16), dim3(256), 0, stream,
                     out_nodes, W2, Y);
  hipLaunchKernelGGL(edge_fused_kernel, dim3((n + TE - 1) / TE), dim3(256), 0, stream,
                     Y, emb, eidx, tu, W3, Bv, emb_new, n);
}